// Round 4
// baseline (848.890 us; speedup 1.0000x reference)
//
#include <hip/hip_runtime.h>

#define NN 50000
#define NE 800000

// ---------------- degrees (int) ----------------
__global__ void degrees_k(const int* __restrict__ src, const int* __restrict__ dst,
                          int* __restrict__ deg_in, int* __restrict__ deg_out, int E) {
    int e = blockIdx.x * 256 + threadIdx.x;
    if (e < E) {
        atomicAdd(deg_in + dst[e], 1);
        atomicAdd(deg_out + src[e], 1);
    }
}

__global__ void make_inv_k(const int* __restrict__ deg_in, const int* __restrict__ deg_out,
                           float* __restrict__ inv_in, float* __restrict__ inv_out,
                           float* __restrict__ inv_mean, float* __restrict__ bcoef, int n) {
    int i = blockIdx.x * 256 + threadIdx.x;
    if (i < n) {
        int d_in = deg_in[i];
        float di = fmaxf((float)d_in, 1.0f);
        float dq = fmaxf((float)deg_out[i], 1.0f);
        inv_in[i]   = 1.0f / sqrtf(di);
        inv_out[i]  = 1.0f / sqrtf(dq);
        inv_mean[i] = 1.0f / di;
        bcoef[i]    = (d_in > 0) ? 1.0f : 0.0f;
    }
}

// ---------------- exclusive scan of deg_in -> row_start ----------------
__global__ void scan1_k(const int* __restrict__ deg, int* __restrict__ out,
                        int* __restrict__ bsum, int n) {
    __shared__ int ps[256];
    int base = blockIdx.x * 512;
    int t = threadIdx.x;
    int i0 = base + 2 * t, i1 = base + 2 * t + 1;
    int a0 = (i0 < n) ? deg[i0] : 0;
    int a1 = (i1 < n) ? deg[i1] : 0;
    ps[t] = a0 + a1;
    __syncthreads();
    for (int off = 1; off < 256; off <<= 1) {
        int v = (t >= off) ? ps[t - off] : 0;
        __syncthreads();
        ps[t] += v;
        __syncthreads();
    }
    int excl = (t > 0) ? ps[t - 1] : 0;
    if (i0 < n) out[i0] = excl;
    if (i1 < n) out[i1] = excl + a0;
    if (t == 255) bsum[blockIdx.x] = ps[255];
}

__global__ void scan2_k(int* __restrict__ bsum, int nb) {
    __shared__ int s[128];
    int t = threadIdx.x;
    int v = (t < nb) ? bsum[t] : 0;
    s[t] = v;
    __syncthreads();
    for (int off = 1; off < 128; off <<= 1) {
        int u = (t >= off) ? s[t - off] : 0;
        __syncthreads();
        s[t] += u;
        __syncthreads();
    }
    if (t < nb) bsum[t] = s[t] - v;  // exclusive
}

__global__ void scan3_k(int* __restrict__ out, const int* __restrict__ bsum, int n) {
    int i = blockIdx.x * 512 + threadIdx.x * 2;
    int add = bsum[blockIdx.x];
    if (i < n) out[i] += add;
    if (i + 1 < n) out[i + 1] += add;
}

// ---------------- CSR fill ----------------
__global__ void fill_csr_k(const int* __restrict__ src, const int* __restrict__ dst,
                           const int* __restrict__ row_start, int* __restrict__ cursor,
                           int* __restrict__ csr_src, int* __restrict__ csr_eid, int E) {
    int e = blockIdx.x * 256 + threadIdx.x;
    if (e < E) {
        int d = dst[e];
        int p = atomicAdd(cursor + d, 1);
        int idx = row_start[d] + p;
        csr_src[idx] = src[e];
        csr_eid[idx] = e;
    }
}

// ---------------- gather raw edge feats (sum over in-edges) ----------------
__global__ void gather_edge_k(const float* __restrict__ ef, const int* __restrict__ csr_eid,
                              const int* __restrict__ row_start, const int* __restrict__ deg,
                              float* __restrict__ efa, int n) {
    int node = blockIdx.x * 8 + (threadIdx.x >> 5);
    int f = threadIdx.x & 31;
    if (node >= n) return;
    int beg = row_start[node], cnt = deg[node];
    float acc = 0.0f;
    int i = 0;
    for (; i + 3 < cnt; i += 4) {
        int e0 = csr_eid[beg + i];
        int e1 = csr_eid[beg + i + 1];
        int e2 = csr_eid[beg + i + 2];
        int e3 = csr_eid[beg + i + 3];
        acc += ef[(size_t)e0 * 32 + f];
        acc += ef[(size_t)e1 * 32 + f];
        acc += ef[(size_t)e2 * 32 + f];
        acc += ef[(size_t)e3 * 32 + f];
    }
    for (; i < cnt; ++i) acc += ef[(size_t)csr_eid[beg + i] * 32 + f];
    efa[(size_t)node * 32 + f] = acc;
}

// ---------------- gather conv: agg[d] = sum_e hS[src_e]  (hS pre-scaled) ----------------
template <int D>
__global__ __launch_bounds__(D) void gather_conv_k(
    const float* __restrict__ h, int h_stride,
    const int* __restrict__ csr_src, const int* __restrict__ row_start,
    const int* __restrict__ deg, float* __restrict__ agg, int agg_stride) {
    int node = blockIdx.x;
    int f = threadIdx.x;
    int beg = row_start[node], cnt = deg[node];
    float acc = 0.0f;
    int i = 0;
    for (; i + 3 < cnt; i += 4) {
        int s0 = csr_src[beg + i];
        int s1 = csr_src[beg + i + 1];
        int s2 = csr_src[beg + i + 2];
        int s3 = csr_src[beg + i + 3];
        acc += h[(size_t)s0 * h_stride + f];
        acc += h[(size_t)s1 * h_stride + f];
        acc += h[(size_t)s2 * h_stride + f];
        acc += h[(size_t)s3 * h_stride + f];
    }
    for (; i < cnt; ++i) acc += h[(size_t)csr_src[beg + i] * h_stride + f];
    agg[(size_t)node * agg_stride + f] = acc;
}

// ---------------- wave-split GEMM: 4 waves/block, 16 rows/wave, NOUT cols/lane -------------
// A-row loads are wave-uniform (scalar path); W in registers reused across 16 rows.
// Inner loop is pure FMA; scale/bias/posts folded into epilogue:
//   out = posts * relu( scale*dot + bias*brow )
// In-place safe: wave reads only rows it writes; clamped waves store nothing.
template <int D_IN, int D_OUT, bool RELU, bool SCALE, bool BROW, bool POSTS>
__global__ __launch_bounds__(256) void gemm_wave_k(
    const float* __restrict__ in, int in_stride,
    const float* __restrict__ W,       // [D_IN][D_OUT] row-major
    const float* __restrict__ bias,    // [D_OUT]
    const float* __restrict__ scale,   // per-row pre-scale or nullptr
    const float* __restrict__ brow,    // per-row bias coefficient or nullptr
    const float* __restrict__ posts,   // per-row post-scale or nullptr
    float* __restrict__ out, int out_stride, int n) {
    constexpr int TM = 16;
    constexpr int NOUT = (D_OUT + 63) / 64;

    const int lane = threadIdx.x & 63;
    const int wave = __builtin_amdgcn_readfirstlane(threadIdx.x >> 6);
    const int row0 = blockIdx.x * (TM * 4) + wave * TM;

    int f[NOUT], ff[NOUT];
    bool fok[NOUT];
    float bv[NOUT];
#pragma unroll
    for (int o = 0; o < NOUT; ++o) {
        f[o] = lane + 64 * o;
        fok[o] = (f[o] < D_OUT);
        ff[o] = fok[o] ? f[o] : 0;
        bv[o] = bias[ff[o]];
    }

    int rr[TM];
#pragma unroll
    for (int m = 0; m < TM; ++m) rr[m] = min(row0 + m, n - 1);

    float acc[NOUT][TM];
#pragma unroll
    for (int o = 0; o < NOUT; ++o)
#pragma unroll
        for (int m = 0; m < TM; ++m) acc[o][m] = 0.0f;

    for (int k = 0; k < D_IN; k += 8) {
        float w[8][NOUT];
#pragma unroll
        for (int j = 0; j < 8; ++j)
#pragma unroll
            for (int o = 0; o < NOUT; ++o) w[j][o] = W[(k + j) * D_OUT + ff[o]];
#pragma unroll
        for (int m = 0; m < TM; ++m) {
            const float4* rp = (const float4*)(in + (size_t)rr[m] * in_stride + k);
            float4 a0 = rp[0];
            float4 a1 = rp[1];
#pragma unroll
            for (int o = 0; o < NOUT; ++o) {
                acc[o][m] = fmaf(a0.x, w[0][o], acc[o][m]);
                acc[o][m] = fmaf(a0.y, w[1][o], acc[o][m]);
                acc[o][m] = fmaf(a0.z, w[2][o], acc[o][m]);
                acc[o][m] = fmaf(a0.w, w[3][o], acc[o][m]);
                acc[o][m] = fmaf(a1.x, w[4][o], acc[o][m]);
                acc[o][m] = fmaf(a1.y, w[5][o], acc[o][m]);
                acc[o][m] = fmaf(a1.z, w[6][o], acc[o][m]);
                acc[o][m] = fmaf(a1.w, w[7][o], acc[o][m]);
            }
        }
    }

#pragma unroll
    for (int m = 0; m < TM; ++m) {
        int row = row0 + m;
        if (row < n) {
            float sm = SCALE ? scale[row] : 1.0f;
            float bc = BROW ? brow[row] : 1.0f;
            float pm = POSTS ? posts[row] : 1.0f;
#pragma unroll
            for (int o = 0; o < NOUT; ++o) {
                if (!fok[o]) continue;
                float v = SCALE ? fmaf(acc[o][m], sm, BROW ? bv[o] * bc : bv[o])
                                : (acc[o][m] + (BROW ? bv[o] * bc : bv[o]));
                if (RELU) v = fmaxf(v, 0.0f);
                if (POSTS) v *= pm;
                out[(size_t)row * out_stride + f[o]] = v;
            }
        }
    }
}

// ---------------- final 192 -> 2 head ----------------
__global__ void out_layer_k(const float* __restrict__ h, const float* __restrict__ Wo,
                            const float* __restrict__ bo, float* __restrict__ out, int n) {
    int gid = blockIdx.x * 256 + threadIdx.x;
    int node = gid >> 1;
    int c = gid & 1;
    if (node >= n) return;
    const float4* h4 = (const float4*)(h + (size_t)node * 192);
    float acc = bo[c];
#pragma unroll
    for (int i = 0; i < 48; ++i) {
        float4 a = h4[i];
        acc += a.x * Wo[(4 * i + 0) * 2 + c];
        acc += a.y * Wo[(4 * i + 1) * 2 + c];
        acc += a.z * Wo[(4 * i + 2) * 2 + c];
        acc += a.w * Wo[(4 * i + 3) * 2 + c];
    }
    out[(size_t)node * 2 + c] = acc;
}

extern "C" void kernel_launch(void* const* d_in, const int* in_sizes, int n_in,
                              void* d_out, int out_size, void* d_ws, size_t ws_size,
                              hipStream_t stream) {
    const float* node_feats = (const float*)d_in[0];   // [N,64]
    const float* edge_feats = (const float*)d_in[1];   // [E,32]
    const float* Wn  = (const float*)d_in[2];          // [64,96]
    const float* bn  = (const float*)d_in[3];
    const float* We  = (const float*)d_in[4];          // [32,32]
    const float* be  = (const float*)d_in[5];
    const float* Wc0 = (const float*)d_in[6];          // [128,192]
    const float* bc0 = (const float*)d_in[7];
    const float* Wc1 = (const float*)d_in[8];          // [192,192]
    const float* bc1 = (const float*)d_in[9];
    const float* Wl0 = (const float*)d_in[10];         // [192,192]
    const float* bl0 = (const float*)d_in[11];
    const float* Wo  = (const float*)d_in[12];         // [192,2]
    const float* bo  = (const float*)d_in[13];
    const int* src = (const int*)d_in[14];
    const int* dst = (const int*)d_in[15];
    float* out = (float*)d_out;

    const int N = NN, E = NE;

    // ---- workspace layout ----
    int* din       = (int*)d_ws;           // N   (zeroed)
    int* dout      = din + N;              // N   (zeroed)
    int* cursor    = dout + N;             // N   (zeroed)
    int* row_start = cursor + N;           // N
    int* bsum      = row_start + N;        // 128
    int* csr_src   = bsum + 128;           // E
    int* csr_eid   = csr_src + E;          // E
    float* inv_in   = (float*)(csr_eid + E);  // N
    float* inv_out  = inv_in + N;             // N
    float* inv_mean = inv_out + N;            // N
    float* bcoef    = inv_mean + N;           // N
    float* efa      = bcoef + N;              // 32N
    float* h0       = efa + (size_t)32 * N;   // 128N  (pre-scaled by inv_out)
    float* aggA     = h0 + (size_t)128 * N;   // 192N
    float* aggB     = aggA + (size_t)192 * N; // 192N

    hipMemsetAsync(d_ws, 0, (size_t)3 * N * sizeof(int), stream);

    const int nb = (N + 511) / 512;  // 98
    const int GB = (N + 63) / 64;    // 782 blocks for wave-GEMM

    degrees_k<<<dim3((E + 255) / 256), dim3(256), 0, stream>>>(src, dst, din, dout, E);
    make_inv_k<<<dim3((N + 255) / 256), dim3(256), 0, stream>>>(din, dout, inv_in, inv_out,
                                                                inv_mean, bcoef, N);
    scan1_k<<<dim3(nb), dim3(256), 0, stream>>>(din, row_start, bsum, N);
    scan2_k<<<dim3(1), dim3(128), 0, stream>>>(bsum, nb);
    scan3_k<<<dim3(nb), dim3(256), 0, stream>>>(row_start, bsum, N);
    fill_csr_k<<<dim3((E + 255) / 256), dim3(256), 0, stream>>>(src, dst, row_start, cursor,
                                                                csr_src, csr_eid, E);

    // edge aggregation: efa = segment_sum(edge_feats, dst)
    gather_edge_k<<<dim3(N / 8), dim3(256), 0, stream>>>(edge_feats, csr_eid, row_start, din,
                                                         efa, N);
    // h0[:,0:32] = relu((efa*inv_mean)@We + bcoef*be) * inv_out
    gemm_wave_k<32, 32, true, true, true, true><<<dim3(GB), dim3(256), 0, stream>>>(
        efa, 32, We, be, inv_mean, bcoef, inv_out, h0, 128, N);
    // h0[:,32:128] = relu(node_feats@Wn + bn) * inv_out
    gemm_wave_k<64, 96, true, false, false, true><<<dim3(GB), dim3(256), 0, stream>>>(
        node_feats, 64, Wn, bn, nullptr, nullptr, inv_out, h0 + 32, 128, N);

    // conv0: gather h0 -> aggA, then GEMM 128->192 in-place; post-scale inv_out for conv1
    gather_conv_k<128><<<dim3(N), dim3(128), 0, stream>>>(h0, 128, csr_src, row_start,
                                                          din, aggA, 192);
    gemm_wave_k<128, 192, true, true, false, true><<<dim3(GB), dim3(256), 0, stream>>>(
        aggA, 192, Wc0, bc0, inv_in, nullptr, inv_out, aggA, 192, N);

    // conv1: gather aggA -> aggB, GEMM 192->192 in-place (no post-scale)
    gather_conv_k<192><<<dim3(N), dim3(192), 0, stream>>>(aggA, 192, csr_src, row_start,
                                                          din, aggB, 192);
    gemm_wave_k<192, 192, true, true, false, false><<<dim3(GB), dim3(256), 0, stream>>>(
        aggB, 192, Wc1, bc1, inv_in, nullptr, nullptr, aggB, 192, N);

    // linear 192->192: aggB -> aggA
    gemm_wave_k<192, 192, true, false, false, false><<<dim3(GB), dim3(256), 0, stream>>>(
        aggB, 192, Wl0, bl0, nullptr, nullptr, nullptr, aggA, 192, N);

    // head 192->2
    out_layer_k<<<dim3((N * 2 + 255) / 256), dim3(256), 0, stream>>>(aggA, Wo, bo, out, N);
}

// Round 6
// 717.496 us; speedup vs baseline: 1.1831x; 1.1831x over previous
//
#include <hip/hip_runtime.h>

#define NN 50000
#define NE 800000

// ---------------- degrees (int) ----------------
__global__ void degrees_k(const int* __restrict__ src, const int* __restrict__ dst,
                          int* __restrict__ deg_in, int* __restrict__ deg_out, int E) {
    int e = blockIdx.x * 256 + threadIdx.x;
    if (e < E) {
        atomicAdd(deg_in + dst[e], 1);
        atomicAdd(deg_out + src[e], 1);
    }
}

__global__ void make_inv_k(const int* __restrict__ deg_in, const int* __restrict__ deg_out,
                           float* __restrict__ inv_in, float* __restrict__ inv_out,
                           float* __restrict__ inv_mean, float* __restrict__ bcoef, int n) {
    int i = blockIdx.x * 256 + threadIdx.x;
    if (i < n) {
        int d_in = deg_in[i];
        float di = fmaxf((float)d_in, 1.0f);
        float dq = fmaxf((float)deg_out[i], 1.0f);
        inv_in[i]   = 1.0f / sqrtf(di);
        inv_out[i]  = 1.0f / sqrtf(dq);
        inv_mean[i] = 1.0f / di;
        bcoef[i]    = (d_in > 0) ? 1.0f : 0.0f;
    }
}

// ---------------- exclusive scan of deg_in -> row_start ----------------
__global__ void scan1_k(const int* __restrict__ deg, int* __restrict__ out,
                        int* __restrict__ bsum, int n) {
    __shared__ int ps[256];
    int base = blockIdx.x * 512;
    int t = threadIdx.x;
    int i0 = base + 2 * t, i1 = base + 2 * t + 1;
    int a0 = (i0 < n) ? deg[i0] : 0;
    int a1 = (i1 < n) ? deg[i1] : 0;
    ps[t] = a0 + a1;
    __syncthreads();
    for (int off = 1; off < 256; off <<= 1) {
        int v = (t >= off) ? ps[t - off] : 0;
        __syncthreads();
        ps[t] += v;
        __syncthreads();
    }
    int excl = (t > 0) ? ps[t - 1] : 0;
    if (i0 < n) out[i0] = excl;
    if (i1 < n) out[i1] = excl + a0;
    if (t == 255) bsum[blockIdx.x] = ps[255];
}

__global__ void scan2_k(int* __restrict__ bsum, int nb) {
    __shared__ int s[128];
    int t = threadIdx.x;
    int v = (t < nb) ? bsum[t] : 0;
    s[t] = v;
    __syncthreads();
    for (int off = 1; off < 128; off <<= 1) {
        int u = (t >= off) ? s[t - off] : 0;
        __syncthreads();
        s[t] += u;
        __syncthreads();
    }
    if (t < nb) bsum[t] = s[t] - v;  // exclusive
}

__global__ void scan3_k(int* __restrict__ out, const int* __restrict__ bsum, int n) {
    int i = blockIdx.x * 512 + threadIdx.x * 2;
    int add = bsum[blockIdx.x];
    if (i < n) out[i] += add;
    if (i + 1 < n) out[i + 1] += add;
}

// ---------------- CSR fill ----------------
__global__ void fill_csr_k(const int* __restrict__ src, const int* __restrict__ dst,
                           const int* __restrict__ row_start, int* __restrict__ cursor,
                           int* __restrict__ csr_src, int* __restrict__ csr_eid, int E) {
    int e = blockIdx.x * 256 + threadIdx.x;
    if (e < E) {
        int d = dst[e];
        int p = atomicAdd(cursor + d, 1);
        int idx = row_start[d] + p;
        csr_src[idx] = src[e];
        csr_eid[idx] = e;
    }
}

// ---------------- gather raw edge feats (sum over in-edges) ----------------
__global__ void gather_edge_k(const float* __restrict__ ef, const int* __restrict__ csr_eid,
                              const int* __restrict__ row_start, const int* __restrict__ deg,
                              float* __restrict__ efa, int n) {
    int node = blockIdx.x * 8 + (threadIdx.x >> 5);
    int f = threadIdx.x & 31;
    if (node >= n) return;
    int beg = row_start[node], cnt = deg[node];
    float acc = 0.0f;
    int i = 0;
    for (; i + 3 < cnt; i += 4) {
        int e0 = csr_eid[beg + i];
        int e1 = csr_eid[beg + i + 1];
        int e2 = csr_eid[beg + i + 2];
        int e3 = csr_eid[beg + i + 3];
        acc += ef[(size_t)e0 * 32 + f];
        acc += ef[(size_t)e1 * 32 + f];
        acc += ef[(size_t)e2 * 32 + f];
        acc += ef[(size_t)e3 * 32 + f];
    }
    for (; i < cnt; ++i) acc += ef[(size_t)csr_eid[beg + i] * 32 + f];
    efa[(size_t)node * 32 + f] = acc;
}

// ---------------- gather conv: agg[d] = sum_e hS[src_e]  (hS pre-scaled) ----------------
template <int D>
__global__ __launch_bounds__(D) void gather_conv_k(
    const float* __restrict__ h, int h_stride,
    const int* __restrict__ csr_src, const int* __restrict__ row_start,
    const int* __restrict__ deg, float* __restrict__ agg, int agg_stride) {
    int node = blockIdx.x;
    int f = threadIdx.x;
    int beg = row_start[node], cnt = deg[node];
    float acc = 0.0f;
    int i = 0;
    for (; i + 3 < cnt; i += 4) {
        int s0 = csr_src[beg + i];
        int s1 = csr_src[beg + i + 1];
        int s2 = csr_src[beg + i + 2];
        int s3 = csr_src[beg + i + 3];
        acc += h[(size_t)s0 * h_stride + f];
        acc += h[(size_t)s1 * h_stride + f];
        acc += h[(size_t)s2 * h_stride + f];
        acc += h[(size_t)s3 * h_stride + f];
    }
    for (; i < cnt; ++i) acc += h[(size_t)csr_src[beg + i] * h_stride + f];
    agg[(size_t)node * agg_stride + f] = acc;
}

// ---------------- tiled GEMM: 4 waves/block, 8 rows/wave, 3 cols/lane ----------------
// 32 rows staged in LDS (scaled); LDS reads are wave-uniform broadcasts (conflict-free).
// Per wave k-step(4): 96 FMA vs 8 ds_read_b128 + 12 W loads -> ~83% FMA issue slots.
// In-place safe: block stages all its rows before any store.
//   out = posts * relu( (scale*in)@W + bias*brow )
template <int D_IN, int D_OUT, bool RELU, bool SCALE, bool BROW, bool POSTS>
__global__ __launch_bounds__(256) void gemm_tile_k(
    const float* __restrict__ in, int in_stride,
    const float* __restrict__ W,       // [D_IN][D_OUT] row-major
    const float* __restrict__ bias,    // [D_OUT]
    const float* __restrict__ scale,   // per-row pre-scale or nullptr
    const float* __restrict__ brow,    // per-row bias coefficient or nullptr
    const float* __restrict__ posts,   // per-row post-scale or nullptr
    float* __restrict__ out, int out_stride, int n) {
    constexpr int TMW = 8;             // rows per wave
    constexpr int ROWS = TMW * 4;      // 32 rows per block
    constexpr int NOUT = (D_OUT + 63) / 64;
    __shared__ float s_in[ROWS * D_IN];

    const int tid = threadIdx.x;
    const int lane = tid & 63;
    const int wave = tid >> 6;
    const int row0 = blockIdx.x * ROWS;

    // stage ROWS rows (pre-scaled) as float4
    constexpr int NV = ROWS * D_IN / 4;
    for (int i = tid; i < NV; i += 256) {
        int m = i / (D_IN / 4);
        int kv = i % (D_IN / 4);
        int row = min(row0 + m, n - 1);
        float4 v = *(const float4*)(in + (size_t)row * in_stride + kv * 4);
        if (SCALE) {
            float s = scale[row];
            v.x *= s; v.y *= s; v.z *= s; v.w *= s;
        }
        *(float4*)(s_in + m * D_IN + kv * 4) = v;
    }
    __syncthreads();

    int f[NOUT], ff[NOUT];
    bool fok[NOUT];
    float bv[NOUT];
#pragma unroll
    for (int o = 0; o < NOUT; ++o) {
        f[o] = lane + 64 * o;
        fok[o] = (f[o] < D_OUT);
        ff[o] = fok[o] ? f[o] : 0;
        bv[o] = bias[ff[o]];
    }

    const float* s_my = s_in + wave * TMW * D_IN;

    float acc[NOUT][TMW];
#pragma unroll
    for (int o = 0; o < NOUT; ++o)
#pragma unroll
        for (int m = 0; m < TMW; ++m) acc[o][m] = 0.0f;

    for (int k = 0; k < D_IN; k += 4) {
        float w[4][NOUT];
#pragma unroll
        for (int j = 0; j < 4; ++j)
#pragma unroll
            for (int o = 0; o < NOUT; ++o) w[j][o] = W[(k + j) * D_OUT + ff[o]];
#pragma unroll
        for (int m = 0; m < TMW; ++m) {
            float4 a = *(const float4*)(s_my + m * D_IN + k);
#pragma unroll
            for (int o = 0; o < NOUT; ++o) {
                acc[o][m] = fmaf(a.x, w[0][o], acc[o][m]);
                acc[o][m] = fmaf(a.y, w[1][o], acc[o][m]);
                acc[o][m] = fmaf(a.z, w[2][o], acc[o][m]);
                acc[o][m] = fmaf(a.w, w[3][o], acc[o][m]);
            }
        }
    }

#pragma unroll
    for (int m = 0; m < TMW; ++m) {
        int row = row0 + wave * TMW + m;
        if (row < n) {
            float bc = BROW ? brow[row] : 1.0f;
            float pm = POSTS ? posts[row] : 1.0f;
#pragma unroll
            for (int o = 0; o < NOUT; ++o) {
                if (!fok[o]) continue;
                float v = acc[o][m] + bv[o] * bc;
                if (RELU) v = fmaxf(v, 0.0f);
                if (POSTS) v *= pm;
                out[(size_t)row * out_stride + f[o]] = v;
            }
        }
    }
}

// ---------------- final 192 -> 2 head ----------------
__global__ void out_layer_k(const float* __restrict__ h, const float* __restrict__ Wo,
                            const float* __restrict__ bo, float* __restrict__ out, int n) {
    int gid = blockIdx.x * 256 + threadIdx.x;
    int node = gid >> 1;
    int c = gid & 1;
    if (node >= n) return;
    const float4* h4 = (const float4*)(h + (size_t)node * 192);
    float acc = bo[c];
#pragma unroll
    for (int i = 0; i < 48; ++i) {
        float4 a = h4[i];
        acc += a.x * Wo[(4 * i + 0) * 2 + c];
        acc += a.y * Wo[(4 * i + 1) * 2 + c];
        acc += a.z * Wo[(4 * i + 2) * 2 + c];
        acc += a.w * Wo[(4 * i + 3) * 2 + c];
    }
    out[(size_t)node * 2 + c] = acc;
}

extern "C" void kernel_launch(void* const* d_in, const int* in_sizes, int n_in,
                              void* d_out, int out_size, void* d_ws, size_t ws_size,
                              hipStream_t stream) {
    const float* node_feats = (const float*)d_in[0];   // [N,64]
    const float* edge_feats = (const float*)d_in[1];   // [E,32]
    const float* Wn  = (const float*)d_in[2];          // [64,96]
    const float* bn  = (const float*)d_in[3];
    const float* We  = (const float*)d_in[4];          // [32,32]
    const float* be  = (const float*)d_in[5];
    const float* Wc0 = (const float*)d_in[6];          // [128,192]
    const float* bc0 = (const float*)d_in[7];
    const float* Wc1 = (const float*)d_in[8];          // [192,192]
    const float* bc1 = (const float*)d_in[9];
    const float* Wl0 = (const float*)d_in[10];         // [192,192]
    const float* bl0 = (const float*)d_in[11];
    const float* Wo  = (const float*)d_in[12];         // [192,2]
    const float* bo  = (const float*)d_in[13];
    const int* src = (const int*)d_in[14];
    const int* dst = (const int*)d_in[15];
    float* out = (float*)d_out;

    const int N = NN, E = NE;

    // ---- workspace layout ----
    int* din       = (int*)d_ws;           // N   (zeroed)
    int* dout      = din + N;              // N   (zeroed)
    int* cursor    = dout + N;             // N   (zeroed)
    int* row_start = cursor + N;           // N
    int* bsum      = row_start + N;        // 128
    int* csr_src   = bsum + 128;           // E
    int* csr_eid   = csr_src + E;          // E
    float* inv_in   = (float*)(csr_eid + E);  // N
    float* inv_out  = inv_in + N;             // N
    float* inv_mean = inv_out + N;            // N
    float* bcoef    = inv_mean + N;           // N
    float* efa      = bcoef + N;              // 32N
    float* h0       = efa + (size_t)32 * N;   // 128N  (pre-scaled by inv_out)
    float* aggA     = h0 + (size_t)128 * N;   // 192N
    float* aggB     = aggA + (size_t)192 * N; // 192N

    hipMemsetAsync(d_ws, 0, (size_t)3 * N * sizeof(int), stream);

    const int nb = (N + 511) / 512;  // 98
    const int GB = (N + 31) / 32;    // 1563 blocks for tiled GEMM

    degrees_k<<<dim3((E + 255) / 256), dim3(256), 0, stream>>>(src, dst, din, dout, E);
    make_inv_k<<<dim3((N + 255) / 256), dim3(256), 0, stream>>>(din, dout, inv_in, inv_out,
                                                                inv_mean, bcoef, N);
    scan1_k<<<dim3(nb), dim3(256), 0, stream>>>(din, row_start, bsum, N);
    scan2_k<<<dim3(1), dim3(128), 0, stream>>>(bsum, nb);
    scan3_k<<<dim3(nb), dim3(256), 0, stream>>>(row_start, bsum, N);
    fill_csr_k<<<dim3((E + 255) / 256), dim3(256), 0, stream>>>(src, dst, row_start, cursor,
                                                                csr_src, csr_eid, E);

    // edge aggregation: efa = segment_sum(edge_feats, dst)
    gather_edge_k<<<dim3(N / 8), dim3(256), 0, stream>>>(edge_feats, csr_eid, row_start, din,
                                                         efa, N);
    // h0[:,0:32] = relu((efa*inv_mean)@We + bcoef*be) * inv_out
    gemm_tile_k<32, 32, true, true, true, true><<<dim3(GB), dim3(256), 0, stream>>>(
        efa, 32, We, be, inv_mean, bcoef, inv_out, h0, 128, N);
    // h0[:,32:128] = relu(node_feats@Wn + bn) * inv_out
    gemm_tile_k<64, 96, true, false, false, true><<<dim3(GB), dim3(256), 0, stream>>>(
        node_feats, 64, Wn, bn, nullptr, nullptr, inv_out, h0 + 32, 128, N);

    // conv0: gather h0 -> aggA, then GEMM 128->192 in-place; post-scale inv_out for conv1
    gather_conv_k<128><<<dim3(N), dim3(128), 0, stream>>>(h0, 128, csr_src, row_start,
                                                          din, aggA, 192);
    gemm_tile_k<128, 192, true, true, false, true><<<dim3(GB), dim3(256), 0, stream>>>(
        aggA, 192, Wc0, bc0, inv_in, nullptr, inv_out, aggA, 192, N);

    // conv1: gather aggA -> aggB, GEMM 192->192 in-place (no post-scale)
    gather_conv_k<192><<<dim3(N), dim3(192), 0, stream>>>(aggA, 192, csr_src, row_start,
                                                          din, aggB, 192);
    gemm_tile_k<192, 192, true, true, false, false><<<dim3(GB), dim3(256), 0, stream>>>(
        aggB, 192, Wc1, bc1, inv_in, nullptr, nullptr, aggB, 192, N);

    // linear 192->192: aggB -> aggA
    gemm_tile_k<192, 192, true, false, false, false><<<dim3(GB), dim3(256), 0, stream>>>(
        aggB, 192, Wl0, bl0, nullptr, nullptr, nullptr, aggA, 192, N);

    // head 192->2
    out_layer_k<<<dim3((N * 2 + 255) / 256), dim3(256), 0, stream>>>(aggA, Wo, bo, out, N);
}

// Round 7
// 698.519 us; speedup vs baseline: 1.2153x; 1.0272x over previous
//
#include <hip/hip_runtime.h>

#define NN 50000
#define NE 800000

// ---------------- degrees (int) ----------------
__global__ void degrees_k(const int* __restrict__ src, const int* __restrict__ dst,
                          int* __restrict__ deg_in, int* __restrict__ deg_out, int E) {
    int e = blockIdx.x * 256 + threadIdx.x;
    if (e < E) {
        atomicAdd(deg_in + dst[e], 1);
        atomicAdd(deg_out + src[e], 1);
    }
}

__global__ void make_inv_k(const int* __restrict__ deg_in, const int* __restrict__ deg_out,
                           float* __restrict__ inv_in, float* __restrict__ inv_out,
                           float* __restrict__ inv_mean, float* __restrict__ bcoef, int n) {
    int i = blockIdx.x * 256 + threadIdx.x;
    if (i < n) {
        int d_in = deg_in[i];
        float di = fmaxf((float)d_in, 1.0f);
        float dq = fmaxf((float)deg_out[i], 1.0f);
        inv_in[i]   = 1.0f / sqrtf(di);
        inv_out[i]  = 1.0f / sqrtf(dq);
        inv_mean[i] = 1.0f / di;
        bcoef[i]    = (d_in > 0) ? 1.0f : 0.0f;
    }
}

// ---------------- exclusive scan of deg_in -> row_start ----------------
__global__ void scan1_k(const int* __restrict__ deg, int* __restrict__ out,
                        int* __restrict__ bsum, int n) {
    __shared__ int ps[256];
    int base = blockIdx.x * 512;
    int t = threadIdx.x;
    int i0 = base + 2 * t, i1 = base + 2 * t + 1;
    int a0 = (i0 < n) ? deg[i0] : 0;
    int a1 = (i1 < n) ? deg[i1] : 0;
    ps[t] = a0 + a1;
    __syncthreads();
    for (int off = 1; off < 256; off <<= 1) {
        int v = (t >= off) ? ps[t - off] : 0;
        __syncthreads();
        ps[t] += v;
        __syncthreads();
    }
    int excl = (t > 0) ? ps[t - 1] : 0;
    if (i0 < n) out[i0] = excl;
    if (i1 < n) out[i1] = excl + a0;
    if (t == 255) bsum[blockIdx.x] = ps[255];
}

__global__ void scan2_k(int* __restrict__ bsum, int nb) {
    __shared__ int s[128];
    int t = threadIdx.x;
    int v = (t < nb) ? bsum[t] : 0;
    s[t] = v;
    __syncthreads();
    for (int off = 1; off < 128; off <<= 1) {
        int u = (t >= off) ? s[t - off] : 0;
        __syncthreads();
        s[t] += u;
        __syncthreads();
    }
    if (t < nb) bsum[t] = s[t] - v;  // exclusive
}

__global__ void scan3_k(int* __restrict__ out, const int* __restrict__ bsum, int n) {
    int i = blockIdx.x * 512 + threadIdx.x * 2;
    int add = bsum[blockIdx.x];
    if (i < n) out[i] += add;
    if (i + 1 < n) out[i + 1] += add;
}

// ---------------- CSR fill ----------------
__global__ void fill_csr_k(const int* __restrict__ src, const int* __restrict__ dst,
                           const int* __restrict__ row_start, int* __restrict__ cursor,
                           int* __restrict__ csr_src, int* __restrict__ csr_eid, int E) {
    int e = blockIdx.x * 256 + threadIdx.x;
    if (e < E) {
        int d = dst[e];
        int p = atomicAdd(cursor + d, 1);
        int idx = row_start[d] + p;
        csr_src[idx] = src[e];
        csr_eid[idx] = e;
    }
}

// ---------------- gather raw edge feats (sum over in-edges) ----------------
__global__ void gather_edge_k(const float* __restrict__ ef, const int* __restrict__ csr_eid,
                              const int* __restrict__ row_start, const int* __restrict__ deg,
                              float* __restrict__ efa, int n) {
    int node = blockIdx.x * 8 + (threadIdx.x >> 5);
    int f = threadIdx.x & 31;
    if (node >= n) return;
    int beg = row_start[node], cnt = deg[node];
    float acc = 0.0f;
    int i = 0;
    for (; i + 3 < cnt; i += 4) {
        int e0 = csr_eid[beg + i];
        int e1 = csr_eid[beg + i + 1];
        int e2 = csr_eid[beg + i + 2];
        int e3 = csr_eid[beg + i + 3];
        acc += ef[(size_t)e0 * 32 + f];
        acc += ef[(size_t)e1 * 32 + f];
        acc += ef[(size_t)e2 * 32 + f];
        acc += ef[(size_t)e3 * 32 + f];
    }
    for (; i < cnt; ++i) acc += ef[(size_t)csr_eid[beg + i] * 32 + f];
    efa[(size_t)node * 32 + f] = acc;
}

// ---------------- gather conv: agg[d] = sum_e hS[src_e]  (hS pre-scaled) ----------------
template <int D>
__global__ __launch_bounds__(D) void gather_conv_k(
    const float* __restrict__ h, int h_stride,
    const int* __restrict__ csr_src, const int* __restrict__ row_start,
    const int* __restrict__ deg, float* __restrict__ agg, int agg_stride) {
    int node = blockIdx.x;
    int f = threadIdx.x;
    int beg = row_start[node], cnt = deg[node];
    float acc = 0.0f;
    int i = 0;
    for (; i + 3 < cnt; i += 4) {
        int s0 = csr_src[beg + i];
        int s1 = csr_src[beg + i + 1];
        int s2 = csr_src[beg + i + 2];
        int s3 = csr_src[beg + i + 3];
        acc += h[(size_t)s0 * h_stride + f];
        acc += h[(size_t)s1 * h_stride + f];
        acc += h[(size_t)s2 * h_stride + f];
        acc += h[(size_t)s3 * h_stride + f];
    }
    for (; i < cnt; ++i) acc += h[(size_t)csr_src[beg + i] * h_stride + f];
    agg[(size_t)node * agg_stride + f] = acc;
}

// ---------------- small tiled GEMM (round-6 structure, for 32->32 and 64->96) -------------
template <int D_IN, int D_OUT, bool RELU, bool SCALE, bool BROW, bool POSTS>
__global__ __launch_bounds__(256) void gemm_tile_k(
    const float* __restrict__ in, int in_stride,
    const float* __restrict__ W, const float* __restrict__ bias,
    const float* __restrict__ scale, const float* __restrict__ brow,
    const float* __restrict__ posts,
    float* __restrict__ out, int out_stride, int n) {
    constexpr int TMW = 8;
    constexpr int ROWS = TMW * 4;
    constexpr int NOUT = (D_OUT + 63) / 64;
    __shared__ float s_in[ROWS * D_IN];

    const int tid = threadIdx.x;
    const int lane = tid & 63;
    const int wave = tid >> 6;
    const int row0 = blockIdx.x * ROWS;

    constexpr int NV = ROWS * D_IN / 4;
    for (int i = tid; i < NV; i += 256) {
        int m = i / (D_IN / 4);
        int kv = i % (D_IN / 4);
        int row = min(row0 + m, n - 1);
        float4 v = *(const float4*)(in + (size_t)row * in_stride + kv * 4);
        if (SCALE) {
            float s = scale[row];
            v.x *= s; v.y *= s; v.z *= s; v.w *= s;
        }
        *(float4*)(s_in + m * D_IN + kv * 4) = v;
    }
    __syncthreads();

    int f[NOUT], ff[NOUT];
    bool fok[NOUT];
    float bv[NOUT];
#pragma unroll
    for (int o = 0; o < NOUT; ++o) {
        f[o] = lane + 64 * o;
        fok[o] = (f[o] < D_OUT);
        ff[o] = fok[o] ? f[o] : 0;
        bv[o] = bias[ff[o]];
    }

    const float* s_my = s_in + wave * TMW * D_IN;

    float acc[NOUT][TMW];
#pragma unroll
    for (int o = 0; o < NOUT; ++o)
#pragma unroll
        for (int m = 0; m < TMW; ++m) acc[o][m] = 0.0f;

    for (int k = 0; k < D_IN; k += 4) {
        float w[4][NOUT];
#pragma unroll
        for (int j = 0; j < 4; ++j)
#pragma unroll
            for (int o = 0; o < NOUT; ++o) w[j][o] = W[(k + j) * D_OUT + ff[o]];
#pragma unroll
        for (int m = 0; m < TMW; ++m) {
            float4 a = *(const float4*)(s_my + m * D_IN + k);
#pragma unroll
            for (int o = 0; o < NOUT; ++o) {
                acc[o][m] = fmaf(a.x, w[0][o], acc[o][m]);
                acc[o][m] = fmaf(a.y, w[1][o], acc[o][m]);
                acc[o][m] = fmaf(a.z, w[2][o], acc[o][m]);
                acc[o][m] = fmaf(a.w, w[3][o], acc[o][m]);
            }
        }
    }

#pragma unroll
    for (int m = 0; m < TMW; ++m) {
        int row = row0 + wave * TMW + m;
        if (row < n) {
            float bc = BROW ? brow[row] : 1.0f;
            float pm = POSTS ? posts[row] : 1.0f;
#pragma unroll
            for (int o = 0; o < NOUT; ++o) {
                if (!fok[o]) continue;
                float v = acc[o][m] + bv[o] * bc;
                if (RELU) v = fmaxf(v, 0.0f);
                if (POSTS) v *= pm;
                out[(size_t)row * out_stride + f[o]] = v;
            }
        }
    }
}

// ---------------- K-split GEMM: 256 thr = 2 row-groups x 2 K-halves over 16-row tile ------
// 16 rows staged in 12.3 KB LDS shared by all 4 waves; partials reduced through same LDS.
//   out = posts * relu( (scale*in)@W + bias )
template <int D_IN, int D_OUT, bool RELU, bool SCALE, bool POSTS>
__global__ __launch_bounds__(256) void gemm_ks_k(
    const float* __restrict__ in, int in_stride,
    const float* __restrict__ W, const float* __restrict__ bias,
    const float* __restrict__ scale, const float* __restrict__ posts,
    float* __restrict__ out, int out_stride, int n) {
    constexpr int ROWS = 16;
    constexpr int TMW = 8;
    constexpr int NOUT = (D_OUT + 63) / 64;
    constexpr int KH = D_IN / 2;
    constexpr int SW = (D_OUT > D_IN ? D_OUT : D_IN);
    __shared__ float s[ROWS * SW];

    const int tid = threadIdx.x;
    const int lane = tid & 63;
    const int wave = tid >> 6;
    const int rg = wave & 1;   // row group
    const int kh = wave >> 1;  // k half
    const int row0 = blockIdx.x * ROWS;

    constexpr int NV = ROWS * D_IN / 4;
    for (int i = tid; i < NV; i += 256) {
        int m = i / (D_IN / 4);
        int kv = i % (D_IN / 4);
        int row = min(row0 + m, n - 1);
        float4 v = *(const float4*)(in + (size_t)row * in_stride + kv * 4);
        if (SCALE) {
            float sc = scale[row];
            v.x *= sc; v.y *= sc; v.z *= sc; v.w *= sc;
        }
        *(float4*)(s + m * D_IN + kv * 4) = v;
    }
    __syncthreads();

    int f[NOUT], ff[NOUT];
    bool fok[NOUT];
    float bv[NOUT];
#pragma unroll
    for (int o = 0; o < NOUT; ++o) {
        f[o] = lane + 64 * o;
        fok[o] = (f[o] < D_OUT);
        ff[o] = fok[o] ? f[o] : 0;
        bv[o] = bias[ff[o]];
    }

    const float* s_my = s + rg * TMW * D_IN;
    const int k0 = kh * KH;

    float acc[NOUT][TMW];
#pragma unroll
    for (int o = 0; o < NOUT; ++o)
#pragma unroll
        for (int m = 0; m < TMW; ++m) acc[o][m] = 0.0f;

    for (int k = k0; k < k0 + KH; k += 4) {
        float w[4][NOUT];
#pragma unroll
        for (int j = 0; j < 4; ++j)
#pragma unroll
            for (int o = 0; o < NOUT; ++o) w[j][o] = W[(k + j) * D_OUT + ff[o]];
#pragma unroll
        for (int m = 0; m < TMW; ++m) {
            float4 a = *(const float4*)(s_my + m * D_IN + k);
#pragma unroll
            for (int o = 0; o < NOUT; ++o) {
                acc[o][m] = fmaf(a.x, w[0][o], acc[o][m]);
                acc[o][m] = fmaf(a.y, w[1][o], acc[o][m]);
                acc[o][m] = fmaf(a.z, w[2][o], acc[o][m]);
                acc[o][m] = fmaf(a.w, w[3][o], acc[o][m]);
            }
        }
    }

    __syncthreads();  // A dead; reuse s for partials
    if (kh == 1) {
#pragma unroll
        for (int m = 0; m < TMW; ++m)
#pragma unroll
            for (int o = 0; o < NOUT; ++o)
                if (fok[o]) s[(rg * TMW + m) * D_OUT + f[o]] = acc[o][m];
    }
    __syncthreads();
    if (kh == 0) {
#pragma unroll
        for (int m = 0; m < TMW; ++m) {
            int row = row0 + rg * TMW + m;
            if (row >= n) continue;
            float pm = POSTS ? posts[row] : 1.0f;
#pragma unroll
            for (int o = 0; o < NOUT; ++o) {
                if (!fok[o]) continue;
                float v = acc[o][m] + s[(rg * TMW + m) * D_OUT + f[o]] + bv[o];
                if (RELU) v = fmaxf(v, 0.0f);
                if (POSTS) v *= pm;
                out[(size_t)row * out_stride + f[o]] = v;
            }
        }
    }
}

// ---------------- fused conv1-GEMM + linear-GEMM (192->192->192), K-split ------------------
//   h2 = relu( (scale*in)@W1 + b1 )   [stays in LDS]
//   out = relu( h2@W2 + b2 )
__global__ __launch_bounds__(256) void gemm_fused2_k(
    const float* __restrict__ in,   // [n,192]
    const float* __restrict__ W1, const float* __restrict__ b1,
    const float* __restrict__ W2, const float* __restrict__ b2,
    const float* __restrict__ scale,
    float* __restrict__ out, int n) {
    constexpr int D = 192;
    constexpr int ROWS = 16;
    constexpr int TMW = 8;
    constexpr int NOUT = 3;
    constexpr int KH = D / 2;
    __shared__ float s[ROWS * D];

    const int tid = threadIdx.x;
    const int lane = tid & 63;
    const int wave = tid >> 6;
    const int rg = wave & 1;
    const int kh = wave >> 1;
    const int row0 = blockIdx.x * ROWS;

    constexpr int NV = ROWS * D / 4;
    for (int i = tid; i < NV; i += 256) {
        int m = i / (D / 4);
        int kv = i % (D / 4);
        int row = min(row0 + m, n - 1);
        float4 v = *(const float4*)(in + (size_t)row * D + kv * 4);
        float sc = scale[row];
        v.x *= sc; v.y *= sc; v.z *= sc; v.w *= sc;
        *(float4*)(s + m * D + kv * 4) = v;
    }
    __syncthreads();

    int f[NOUT];
    float bv1[NOUT], bv2[NOUT];
#pragma unroll
    for (int o = 0; o < NOUT; ++o) {
        f[o] = lane + 64 * o;
        bv1[o] = b1[f[o]];
        bv2[o] = b2[f[o]];
    }

    const float* s_my = s + rg * TMW * D;
    const int k0 = kh * KH;

    float acc[NOUT][TMW];
#pragma unroll
    for (int o = 0; o < NOUT; ++o)
#pragma unroll
        for (int m = 0; m < TMW; ++m) acc[o][m] = 0.0f;

    // ---- GEMM 1 (W1) ----
    for (int k = k0; k < k0 + KH; k += 4) {
        float w[4][NOUT];
#pragma unroll
        for (int j = 0; j < 4; ++j)
#pragma unroll
            for (int o = 0; o < NOUT; ++o) w[j][o] = W1[(k + j) * D + f[o]];
#pragma unroll
        for (int m = 0; m < TMW; ++m) {
            float4 a = *(const float4*)(s_my + m * D + k);
#pragma unroll
            for (int o = 0; o < NOUT; ++o) {
                acc[o][m] = fmaf(a.x, w[0][o], acc[o][m]);
                acc[o][m] = fmaf(a.y, w[1][o], acc[o][m]);
                acc[o][m] = fmaf(a.z, w[2][o], acc[o][m]);
                acc[o][m] = fmaf(a.w, w[3][o], acc[o][m]);
            }
        }
    }

    __syncthreads();  // A dead
    if (kh == 1) {
#pragma unroll
        for (int m = 0; m < TMW; ++m)
#pragma unroll
            for (int o = 0; o < NOUT; ++o)
                s[(rg * TMW + m) * D + f[o]] = acc[o][m];
    }
    __syncthreads();
    if (kh == 0) {
#pragma unroll
        for (int m = 0; m < TMW; ++m) {
#pragma unroll
            for (int o = 0; o < NOUT; ++o) {
                float v = acc[o][m] + s[(rg * TMW + m) * D + f[o]] + bv1[o];
                s[(rg * TMW + m) * D + f[o]] = fmaxf(v, 0.0f);  // h2 into LDS
            }
        }
    }
    __syncthreads();

    // ---- GEMM 2 (W2), A = h2 in LDS ----
#pragma unroll
    for (int o = 0; o < NOUT; ++o)
#pragma unroll
        for (int m = 0; m < TMW; ++m) acc[o][m] = 0.0f;

    for (int k = k0; k < k0 + KH; k += 4) {
        float w[4][NOUT];
#pragma unroll
        for (int j = 0; j < 4; ++j)
#pragma unroll
            for (int o = 0; o < NOUT; ++o) w[j][o] = W2[(k + j) * D + f[o]];
#pragma unroll
        for (int m = 0; m < TMW; ++m) {
            float4 a = *(const float4*)(s_my + m * D + k);
#pragma unroll
            for (int o = 0; o < NOUT; ++o) {
                acc[o][m] = fmaf(a.x, w[0][o], acc[o][m]);
                acc[o][m] = fmaf(a.y, w[1][o], acc[o][m]);
                acc[o][m] = fmaf(a.z, w[2][o], acc[o][m]);
                acc[o][m] = fmaf(a.w, w[3][o], acc[o][m]);
            }
        }
    }

    __syncthreads();
    if (kh == 1) {
#pragma unroll
        for (int m = 0; m < TMW; ++m)
#pragma unroll
            for (int o = 0; o < NOUT; ++o)
                s[(rg * TMW + m) * D + f[o]] = acc[o][m];
    }
    __syncthreads();
    if (kh == 0) {
#pragma unroll
        for (int m = 0; m < TMW; ++m) {
            int row = row0 + rg * TMW + m;
            if (row >= n) continue;
#pragma unroll
            for (int o = 0; o < NOUT; ++o) {
                float v = acc[o][m] + s[(rg * TMW + m) * D + f[o]] + bv2[o];
                out[(size_t)row * D + f[o]] = fmaxf(v, 0.0f);
            }
        }
    }
}

// ---------------- final 192 -> 2 head ----------------
__global__ void out_layer_k(const float* __restrict__ h, const float* __restrict__ Wo,
                            const float* __restrict__ bo, float* __restrict__ out, int n) {
    int gid = blockIdx.x * 256 + threadIdx.x;
    int node = gid >> 1;
    int c = gid & 1;
    if (node >= n) return;
    const float4* h4 = (const float4*)(h + (size_t)node * 192);
    float acc = bo[c];
#pragma unroll
    for (int i = 0; i < 48; ++i) {
        float4 a = h4[i];
        acc += a.x * Wo[(4 * i + 0) * 2 + c];
        acc += a.y * Wo[(4 * i + 1) * 2 + c];
        acc += a.z * Wo[(4 * i + 2) * 2 + c];
        acc += a.w * Wo[(4 * i + 3) * 2 + c];
    }
    out[(size_t)node * 2 + c] = acc;
}

extern "C" void kernel_launch(void* const* d_in, const int* in_sizes, int n_in,
                              void* d_out, int out_size, void* d_ws, size_t ws_size,
                              hipStream_t stream) {
    const float* node_feats = (const float*)d_in[0];   // [N,64]
    const float* edge_feats = (const float*)d_in[1];   // [E,32]
    const float* Wn  = (const float*)d_in[2];          // [64,96]
    const float* bn  = (const float*)d_in[3];
    const float* We  = (const float*)d_in[4];          // [32,32]
    const float* be  = (const float*)d_in[5];
    const float* Wc0 = (const float*)d_in[6];          // [128,192]
    const float* bc0 = (const float*)d_in[7];
    const float* Wc1 = (const float*)d_in[8];          // [192,192]
    const float* bc1 = (const float*)d_in[9];
    const float* Wl0 = (const float*)d_in[10];         // [192,192]
    const float* bl0 = (const float*)d_in[11];
    const float* Wo  = (const float*)d_in[12];         // [192,2]
    const float* bo  = (const float*)d_in[13];
    const int* src = (const int*)d_in[14];
    const int* dst = (const int*)d_in[15];
    float* out = (float*)d_out;

    const int N = NN, E = NE;

    // ---- workspace layout ----
    int* din       = (int*)d_ws;           // N   (zeroed)
    int* dout      = din + N;              // N   (zeroed)
    int* cursor    = dout + N;             // N   (zeroed)
    int* row_start = cursor + N;           // N
    int* bsum      = row_start + N;        // 128
    int* csr_src   = bsum + 128;           // E
    int* csr_eid   = csr_src + E;          // E
    float* inv_in   = (float*)(csr_eid + E);  // N
    float* inv_out  = inv_in + N;             // N
    float* inv_mean = inv_out + N;            // N
    float* bcoef    = inv_mean + N;           // N
    float* efa      = bcoef + N;              // 32N
    float* h0       = efa + (size_t)32 * N;   // 128N  (pre-scaled by inv_out)
    float* aggA     = h0 + (size_t)128 * N;   // 192N
    float* aggB     = aggA + (size_t)192 * N; // 192N

    hipMemsetAsync(d_ws, 0, (size_t)3 * N * sizeof(int), stream);

    const int nb = (N + 511) / 512;   // 98
    const int GB32 = (N + 31) / 32;   // small-GEMM grid
    const int GB16 = (N + 15) / 16;   // ksplit grid (3125)

    degrees_k<<<dim3((E + 255) / 256), dim3(256), 0, stream>>>(src, dst, din, dout, E);
    make_inv_k<<<dim3((N + 255) / 256), dim3(256), 0, stream>>>(din, dout, inv_in, inv_out,
                                                                inv_mean, bcoef, N);
    scan1_k<<<dim3(nb), dim3(256), 0, stream>>>(din, row_start, bsum, N);
    scan2_k<<<dim3(1), dim3(128), 0, stream>>>(bsum, nb);
    scan3_k<<<dim3(nb), dim3(256), 0, stream>>>(row_start, bsum, N);
    fill_csr_k<<<dim3((E + 255) / 256), dim3(256), 0, stream>>>(src, dst, row_start, cursor,
                                                                csr_src, csr_eid, E);

    // edge aggregation: efa = segment_sum(edge_feats, dst)
    gather_edge_k<<<dim3(N / 8), dim3(256), 0, stream>>>(edge_feats, csr_eid, row_start, din,
                                                         efa, N);
    // h0[:,0:32] = relu((efa*inv_mean)@We + bcoef*be) * inv_out
    gemm_tile_k<32, 32, true, true, true, true><<<dim3(GB32), dim3(256), 0, stream>>>(
        efa, 32, We, be, inv_mean, bcoef, inv_out, h0, 128, N);
    // h0[:,32:128] = relu(node_feats@Wn + bn) * inv_out
    gemm_tile_k<64, 96, true, false, false, true><<<dim3(GB32), dim3(256), 0, stream>>>(
        node_feats, 64, Wn, bn, nullptr, nullptr, inv_out, h0 + 32, 128, N);

    // conv0: gather h0 -> aggA, then K-split GEMM 128->192 in-place; post-scale inv_out
    gather_conv_k<128><<<dim3(N), dim3(128), 0, stream>>>(h0, 128, csr_src, row_start,
                                                          din, aggA, 192);
    gemm_ks_k<128, 192, true, true, true><<<dim3(GB16), dim3(256), 0, stream>>>(
        aggA, 192, Wc0, bc0, inv_in, inv_out, aggA, 192, N);

    // conv1: gather aggA -> aggB, then fused (conv1 GEMM + linear GEMM) -> aggA
    gather_conv_k<192><<<dim3(N), dim3(192), 0, stream>>>(aggA, 192, csr_src, row_start,
                                                          din, aggB, 192);
    gemm_fused2_k<<<dim3(GB16), dim3(256), 0, stream>>>(aggB, Wc1, bc1, Wl0, bl0, inv_in,
                                                        aggA, N);

    // head 192->2
    out_layer_k<<<dim3((N * 2 + 255) / 256), dim3(256), 0, stream>>>(aggA, Wo, bo, out, N);
}